// Round 20
// baseline (105.482 us; speedup 1.0000x reference)
//
#include <hip/hip_runtime.h>

#define B 256
#define EPSV 1e-5f

// ---------- output offsets (f32 elements) ----------
#define OFF_ASSIGN 0
#define OFF_LOSS   256
#define OFF_ACT4   257
#define OFF_L1     2817
#define OFF_L2     12847873
#define OFF_L3     14486273

__device__ __forceinline__ void wave_reduce2(float& s, float& q) {
#pragma unroll
    for (int o = 32; o > 0; o >>= 1) {
        s += __shfl_down(s, o, 64);
        q += __shfl_down(q, o, 64);
    }
}

// K1: conv1 (blocks 0..1535) + w1/k3s transpose (blocks 1536..1963)
__global__ __launch_bounds__(256) void conv1_kernel(
        const float* __restrict__ inp, const float* __restrict__ w,
        const float* __restrict__ bias, float* __restrict__ c1,
        float* __restrict__ part,
        const float* __restrict__ w1, const float* __restrict__ k3,
        float* __restrict__ w1t, float* __restrict__ k3st) {
    int bc = blockIdx.x;
    int tid = threadIdx.x;
    if (bc >= 1536) {
        int idx = (bc - 1536) * 256 + tid;
        if (idx < 48000) {
            int c = idx / 120, o = idx % 120;
            w1t[idx] = w1[o * 400 + c];
        } else if (idx < 48000 + 61440) {
            int j = idx - 48000;
            int c = j >> 9, k = j & 511;
            k3st[j] = k3[k * 120 + c];
        }
        return;
    }
    int b = bc / 6, c = bc % 6;
    __shared__ float ws[75];
    __shared__ float rs[4], rq[4];
    if (tid < 75) ws[tid] = w[c * 75 + tid];
    __syncthreads();
    const float* ip = inp + b * 3072;
    float bs = bias[c];
    float s = 0.f, sq = 0.f;
    for (int hw = tid; hw < 784; hw += 256) {
        int oh = hw / 28, ow = hw % 28;
        float acc = bs;
#pragma unroll
        for (int ic = 0; ic < 3; ++ic) {
            const float* ipc = ip + ic * 1024 + oh * 32 + ow;
            const float* wc = ws + ic * 25;
#pragma unroll
            for (int kh = 0; kh < 5; ++kh)
#pragma unroll
                for (int kw = 0; kw < 5; ++kw)
                    acc += ipc[kh * 32 + kw] * wc[kh * 5 + kw];
        }
        c1[bc * 784 + hw] = acc;
        s += acc; sq += acc * acc;
    }
    wave_reduce2(s, sq);
    if ((tid & 63) == 0) { rs[tid >> 6] = s; rq[tid >> 6] = sq; }
    __syncthreads();
    if (tid == 0) {
        part[bc * 2]     = rs[0] + rs[1] + rs[2] + rs[3];
        part[bc * 2 + 1] = rq[0] + rq[1] + rq[2] + rq[3];
    }
}

// K2: one block per b, 1024 thr: stats1 + BN -> LDS + pool, then CONCURRENT
// {logits1 (784 thr, float4 key-broadcasts)} || {conv2 (160 thr, row-register
// caching)} -> sa + c2raw, then per-channel partials.
__global__ __launch_bounds__(1024) void stage1_kernel(
        const float* __restrict__ c1raw, const float* __restrict__ part1,
        const float* __restrict__ g1, const float* __restrict__ bb1,
        const float* __restrict__ k1s,
        const float* __restrict__ c2w, const float* __restrict__ c2b,
        float* __restrict__ out, float* __restrict__ c2raw,
        float* __restrict__ part2) {
    int b = blockIdx.x, tid = threadIdx.x;
    int lane = tid & 63, wid = tid >> 6;     // 16 waves
    __shared__ __align__(16) float act[4704];
    __shared__ __align__(16) float sk1p[512];      // [64][8]: k0..k5, K2, pad
    __shared__ float w2s[2400];
    __shared__ float xp[1176];
    __shared__ __align__(16) float sa[1600];
    __shared__ float chs[6], chq[6], ssc[6], ssh[6];
    if (wid < 6) {                            // stats1: wave = channel
        float s = 0.f, q = 0.f;
#pragma unroll
        for (int j = 0; j < 4; ++j) {
            int bi = lane + 64 * j;
            s += part1[(bi * 6 + wid) * 2];
            q += part1[(bi * 6 + wid) * 2 + 1];
        }
        wave_reduce2(s, q);
        if (lane == 0) { chs[wid] = s; chq[wid] = q; }
    }
    if (tid >= 640 && tid < 1024) {           // load keys into padded layout
        int idx = tid - 640;                  // 0..383
        int k = idx / 6, c = idx - k * 6;
        sk1p[k * 8 + c] = k1s[idx];
    }
    for (int i = tid; i < 2400; i += 1024) w2s[i] = c2w[i];
    __syncthreads();
    if (tid < 6) {
        float m = chs[tid] * (1.f / 200704.f);
        float v = chq[tid] * (1.f / 200704.f) - m * m;
        float sc = g1[tid] * rsqrtf(v + EPSV);
        ssc[tid] = sc; ssh[tid] = bb1[tid] - m * sc;
    }
    if (tid >= 64 && tid < 128) {             // key norms into slot 6 (+zero pad)
        int k = tid - 64;
        float s = 0.f;
#pragma unroll
        for (int c = 0; c < 6; ++c) { float x = sk1p[k * 8 + c]; s += x * x; }
        sk1p[k * 8 + 6] = s;
        sk1p[k * 8 + 7] = 0.f;
    }
    __syncthreads();
    for (int i = tid; i < 4704; i += 1024) {  // BN from global c1raw
        int c = i / 784;
        act[i] = c1raw[b * 4704 + i] * ssc[c] + ssh[c];
    }
    __syncthreads();
    for (int i = tid; i < 1176; i += 1024) {  // pool (all threads)
        int c = i / 196, p = i % 196, ph = p / 14, pw = p % 14;
        const float* ap = act + c * 784 + ph * 56 + pw * 2;
        float m = fmaxf(fmaxf(ap[0], ap[1]), fmaxf(ap[28], ap[29]));
        xp[i] = fmaxf(m, 0.f);
    }
    __syncthreads();
    if (tid < 784) {                          // ---- logits1: float4 key reads ----
        float a0 = act[tid], a1 = act[784 + tid], a2 = act[1568 + tid];
        float a3 = act[2352 + tid], a4 = act[3136 + tid], a5 = act[3920 + tid];
        float A2 = a0*a0 + a1*a1 + a2*a2 + a3*a3 + a4*a4 + a5*a5;
        float* op = out + OFF_L1 + (long)b * 50176 + tid;
#pragma unroll 4
        for (int k = 0; k < 64; ++k) {
            const float4* kp4 = reinterpret_cast<const float4*>(sk1p + k * 8);
            float4 kA = kp4[0], kB = kp4[1];
            float dot = a0*kA.x + a1*kA.y + a2*kA.z + a3*kA.w + a4*kB.x + a5*kB.y;
            *op = -sqrtf(fmaxf(A2 + kB.z - 2.f * dot, 0.f));
            op += 784;
        }
    } else if (tid < 944) {                   // ---- conv2: row-register caching ----
        int j = tid - 784;                    // 0..159
        int c = j / 10, oh = j - c * 10;
        float acc[10];
        float bias2 = c2b[c];
#pragma unroll
        for (int ow = 0; ow < 10; ++ow) acc[ow] = bias2;
        for (int ic = 0; ic < 6; ++ic) {
            const float* xb = xp + ic * 196;
            const float* wpc = w2s + c * 150 + ic * 25;
#pragma unroll
            for (int kh = 0; kh < 5; ++kh) {
                const float* row = xb + (oh + kh) * 14;
                float r[14];
#pragma unroll
                for (int t = 0; t < 14; ++t) r[t] = row[t];
#pragma unroll
                for (int kw = 0; kw < 5; ++kw) {
                    float wgt = wpc[kh * 5 + kw];
#pragma unroll
                    for (int ow = 0; ow < 10; ++ow)
                        acc[ow] += r[ow + kw] * wgt;
                }
            }
        }
        float* sp = sa + c * 100 + oh * 10;
        float* gp = c2raw + b * 1600 + c * 100 + oh * 10;
#pragma unroll
        for (int ow = 0; ow < 10; ++ow) { sp[ow] = acc[ow]; gp[ow] = acc[ow]; }
    }
    __syncthreads();
    {   // partials: wave = channel (16 waves)
        float s = 0.f, q = 0.f;
        if (lane < 100) { float x = sa[wid * 100 + lane]; s = x; q = x * x; }
        if (lane < 36)  { float x = sa[wid * 100 + 64 + lane]; s += x; q += x * x; }
        wave_reduce2(s, q);
        if (lane == 0) { part2[(b * 16 + wid) * 2] = s; part2[(b * 16 + wid) * 2 + 1] = q; }
    }
}

// K3: TWO blocks per b (grid 2B, 2 blocks/CU): both do stats2 + BN -> LDS.
// h==0: logits2 only (float4 key reads). h==1: pool + fc1 + logits3 + act4 +
// rank-NG loss + argmax. Balanced halves; no cross-block communication.
__global__ __launch_bounds__(1024) void stage2_kernel(
        const float* __restrict__ c2raw, const float* __restrict__ part2,
        const float* __restrict__ g2, const float* __restrict__ bb2,
        const float* __restrict__ k2s,
        const float* __restrict__ w1t, const float* __restrict__ f1b,
        const float* __restrict__ f2w, const float* __restrict__ f2b,
        const float* __restrict__ k3st,
        float* __restrict__ out, float* __restrict__ lossb) {
    int b = blockIdx.x >> 1, h = blockIdx.x & 1;
    int tid = threadIdx.x;
    int lane = tid & 63, wid = tid >> 6;     // 16 waves
    __shared__ __align__(16) float sa[1600];
    __shared__ __align__(16) float sk2[1024];
    __shared__ float k2sq2[64];
    __shared__ float chs[16], chq[16], ssc[16], ssh[16];
    __shared__ float xs[400];
    __shared__ float partq[1024];
    __shared__ float a3r[120], a3p[120];
    __shared__ __align__(16) float sv[512];
    __shared__ __align__(16) float pv[1024];
    __shared__ int cntp[1024];
    __shared__ float wsum[8], wmv[8];
    __shared__ int wmi[8];
    {   // stats2: wave = channel (both blocks, redundant)
        float s = 0.f, q = 0.f;
#pragma unroll
        for (int j = 0; j < 4; ++j) {
            int bi = lane + 64 * j;
            s += part2[(bi * 16 + wid) * 2];
            q += part2[(bi * 16 + wid) * 2 + 1];
        }
        wave_reduce2(s, q);
        if (lane == 0) { chs[wid] = s; chq[wid] = q; }
    }
    if (h == 0) sk2[tid] = k2s[tid];
    __syncthreads();
    if (tid < 16) {
        float m = chs[tid] * (1.f / 25600.f);
        float v = chq[tid] * (1.f / 25600.f) - m * m;
        float sc = g2[tid] * rsqrtf(v + EPSV);
        ssc[tid] = sc; ssh[tid] = bb2[tid] - m * sc;
    }
    if (h == 0 && tid >= 64 && tid < 128) {   // key norms
        int k = tid - 64;
        float s = 0.f;
#pragma unroll
        for (int c = 0; c < 16; ++c) { float x = sk2[k * 16 + c]; s += x * x; }
        k2sq2[k] = s;
    }
    __syncthreads();
    for (int i = tid; i < 1600; i += 1024) {  // BN -> LDS (both blocks)
        int c = i / 100;
        sa[i] = c2raw[b * 1600 + i] * ssc[c] + ssh[c];
    }
    __syncthreads();
    if (h == 0) {
        // ---------------- logits2 only ----------------
        if (tid < 800) {
            int kg = tid / 100, hw = tid - kg * 100;
            float a[16], A2 = 0.f;
#pragma unroll
            for (int c = 0; c < 16; ++c) { a[c] = sa[c * 100 + hw]; A2 += a[c] * a[c]; }
            float* op2 = out + OFF_L2 + (long)b * 6400 + kg * 800 + hw;
#pragma unroll
            for (int k = kg * 8; k < kg * 8 + 8; ++k) {
                const float4* kp4 = reinterpret_cast<const float4*>(sk2 + k * 16);
                float4 kA = kp4[0], kB = kp4[1], kC = kp4[2], kD = kp4[3];
                float dot = a[0]*kA.x + a[1]*kA.y + a[2]*kA.z + a[3]*kA.w
                          + a[4]*kB.x + a[5]*kB.y + a[6]*kB.z + a[7]*kB.w
                          + a[8]*kC.x + a[9]*kC.y + a[10]*kC.z + a[11]*kC.w
                          + a[12]*kD.x + a[13]*kD.y + a[14]*kD.z + a[15]*kD.w;
                *op2 = -sqrtf(fmaxf(A2 + k2sq2[k] - 2.f * dot, 0.f));
                op2 += 100;
            }
        }
        return;
    }
    // ---------------- head (h == 1) ----------------
    for (int i = tid; i < 400; i += 1024) {   // pool
        int c = i / 25, p = i % 25, ph = p / 5, pw = p % 5;
        const float* ap = sa + c * 100 + ph * 20 + pw * 2;
        float m = fmaxf(fmaxf(ap[0], ap[1]), fmaxf(ap[10], ap[11]));
        xs[i] = fmaxf(m, 0.f);
    }
    __syncthreads();
    {   // fc1: 8-way K-split, coalesced w1t columns, float2 x-broadcasts
        int o = tid & 127, q8 = tid >> 7;
        float s = 0.f;
        if (o < 120) {
            const float* wp = w1t + (q8 * 50) * 120 + o;
            const float2* xq = reinterpret_cast<const float2*>(xs + q8 * 50);
#pragma unroll 5
            for (int c2 = 0; c2 < 25; ++c2) {
                float2 xv = xq[c2];
                s += xv.x * wp[(2 * c2) * 120] + xv.y * wp[(2 * c2 + 1) * 120];
            }
        }
        partq[q8 * 128 + o] = s;
    }
    __syncthreads();
    if (tid < 120) {
        float acc = f1b[tid];
#pragma unroll
        for (int q8 = 0; q8 < 8; ++q8) acc += partq[q8 * 128 + tid];
        a3r[tid] = acc;
        a3p[tid] = fmaxf(acc, 0.f);
    }
    __syncthreads();
    {   // logits3: 2 threads per key, coalesced k3st columns
        int k = tid & 511, hh = tid >> 9;
        const float* kp = k3st + k;
        float s = 0.f;
#pragma unroll 6
        for (int c = hh * 60; c < hh * 60 + 60; ++c) {
            float d = a3r[c] - kp[c * 512];
            s += d * d;
        }
        pv[hh * 512 + k] = s;
    }
    if (tid < 10) {
        float acc = f2b[tid];
        const float* wp = f2w + tid * 120;
#pragma unroll 8
        for (int c = 0; c < 120; ++c) acc += a3p[c] * wp[c];
        out[OFF_ACT4 + b * 10 + tid] = acc;
    }
    __syncthreads();
    if (tid < 512) {
        float v = -sqrtf(pv[tid] + pv[512 + tid]);
        sv[tid] = v;
        out[OFF_L3 + (long)b * 512 + tid] = v;
    }
    __syncthreads();
    {   // rank scan: 2 threads per value
        int i = tid & 511, hh = tid >> 9;
        float v = sv[i];
        const float4* sv4 = reinterpret_cast<const float4*>(sv);
        int cnt = 0;
#pragma unroll 8
        for (int j4 = hh * 64; j4 < hh * 64 + 64; ++j4) {
            float4 o4 = sv4[j4];
            int jb = j4 * 4;
            cnt += (o4.x < v || (o4.x == v && jb < i)) ? 1 : 0;
            cnt += (o4.y < v || (o4.y == v && jb + 1 < i)) ? 1 : 0;
            cnt += (o4.z < v || (o4.z == v && jb + 2 < i)) ? 1 : 0;
            cnt += (o4.w < v || (o4.w == v && jb + 3 < i)) ? 1 : 0;
        }
        cntp[hh * 512 + i] = cnt;
    }
    __syncthreads();
    if (tid < 512) {
        float v = sv[tid];
        int cnt = cntp[tid] + cntp[512 + tid];
        float contrib = v * v * expf(-(float)cnt);
        float ssum = contrib;
#pragma unroll
        for (int o = 32; o > 0; o >>= 1) ssum += __shfl_down(ssum, o, 64);
        float mv = v; int mi = tid;
#pragma unroll
        for (int o = 32; o > 0; o >>= 1) {
            float ov = __shfl_down(mv, o, 64);
            int oi = __shfl_down(mi, o, 64);
            if (ov > mv || (ov == mv && oi < mi)) { mv = ov; mi = oi; }
        }
        if (lane == 0) { wsum[wid] = ssum; wmv[wid] = mv; wmi[wid] = mi; }
    }
    __syncthreads();
    if (tid == 0) {
        float tot = 0.f;
        float bmv = wmv[0]; int bmi = wmi[0];
#pragma unroll
        for (int w = 0; w < 8; ++w) {
            tot += wsum[w];
            if (wmv[w] > bmv || (wmv[w] == bmv && wmi[w] < bmi)) { bmv = wmv[w]; bmi = wmi[w]; }
        }
        lossb[b] = tot;
        out[OFF_ASSIGN + b] = (float)bmi;
    }
}

__global__ void final_kernel(const float* __restrict__ loss_b, float* __restrict__ out_loss) {
    __shared__ float r[256];
    int tid = threadIdx.x;
    r[tid] = loss_b[tid];
    __syncthreads();
    for (int s = 128; s > 0; s >>= 1) {
        if (tid < s) r[tid] += r[tid + s];
        __syncthreads();
    }
    if (tid == 0) out_loss[0] = r[0] / 256.f;
}

extern "C" void kernel_launch(void* const* d_in, const int* in_sizes, int n_in,
                              void* d_out, int out_size, void* d_ws, size_t ws_size,
                              hipStream_t stream) {
    const float* inp = (const float*)d_in[0];
    const float* c1w = (const float*)d_in[1];
    const float* c1b = (const float*)d_in[2];
    const float* g1  = (const float*)d_in[3];
    const float* bb1 = (const float*)d_in[4];
    const float* c2w = (const float*)d_in[5];
    const float* c2b = (const float*)d_in[6];
    const float* g2  = (const float*)d_in[7];
    const float* bb2 = (const float*)d_in[8];
    const float* f1w = (const float*)d_in[9];
    const float* f1b = (const float*)d_in[10];
    const float* f2w = (const float*)d_in[11];
    const float* f2b = (const float*)d_in[12];
    const float* k1  = (const float*)d_in[13];
    const float* k2  = (const float*)d_in[14];
    const float* k3  = (const float*)d_in[15];
    float* out = (float*)d_out;

    float* W = (float*)d_ws;
    float* part1 = W + 64;              // 3072
    float* c1raw = W + 3136;            // 1204224
    float* c2raw = W + 1207360;         // 409600
    float* part2 = W + 1616960;         // 8192
    float* lossb = W + 1625152;         // 256
    float* w1t   = W + 1625408;         // 48000
    float* k3st  = W + 1673408;         // 61440

    conv1_kernel<<<1964, 256, 0, stream>>>(inp, c1w, c1b, c1raw, part1,
                                           f1w, k3, w1t, k3st);
    stage1_kernel<<<B, 1024, 0, stream>>>(c1raw, part1, g1, bb1, k1, c2w, c2b,
                                          out, c2raw, part2);
    stage2_kernel<<<B * 2, 1024, 0, stream>>>(c2raw, part2, g2, bb2, k2,
                                              w1t, f1b, f2w, f2b, k3st, out, lossb);
    final_kernel<<<1, 256, 0, stream>>>(lossb, out + OFF_LOSS);
}

// Round 21
// 85.965 us; speedup vs baseline: 1.2270x; 1.2270x over previous
//
#include <hip/hip_runtime.h>

#define B 256
#define EPSV 1e-5f

// ---------- output offsets (f32 elements) ----------
#define OFF_ASSIGN 0
#define OFF_LOSS   256
#define OFF_ACT4   257
#define OFF_L1     2817
#define OFF_L2     12847873
#define OFF_L3     14486273

__device__ __forceinline__ void wave_reduce2(float& s, float& q) {
#pragma unroll
    for (int o = 32; o > 0; o >>= 1) {
        s += __shfl_down(s, o, 64);
        q += __shfl_down(q, o, 64);
    }
}

// K1: conv1 (blocks 0..1535) + w1/k3s transpose (blocks 1536..1963)
__global__ __launch_bounds__(256) void conv1_kernel(
        const float* __restrict__ inp, const float* __restrict__ w,
        const float* __restrict__ bias, float* __restrict__ c1,
        float* __restrict__ part,
        const float* __restrict__ w1, const float* __restrict__ k3,
        float* __restrict__ w1t, float* __restrict__ k3st) {
    int bc = blockIdx.x;
    int tid = threadIdx.x;
    if (bc >= 1536) {
        int idx = (bc - 1536) * 256 + tid;
        if (idx < 48000) {
            int c = idx / 120, o = idx % 120;
            w1t[idx] = w1[o * 400 + c];
        } else if (idx < 48000 + 61440) {
            int j = idx - 48000;
            int c = j >> 9, k = j & 511;
            k3st[j] = k3[k * 120 + c];
        }
        return;
    }
    int b = bc / 6, c = bc % 6;
    __shared__ float ws[75];
    __shared__ float rs[4], rq[4];
    if (tid < 75) ws[tid] = w[c * 75 + tid];
    __syncthreads();
    const float* ip = inp + b * 3072;
    float bs = bias[c];
    float s = 0.f, sq = 0.f;
    for (int hw = tid; hw < 784; hw += 256) {
        int oh = hw / 28, ow = hw % 28;
        float acc = bs;
#pragma unroll
        for (int ic = 0; ic < 3; ++ic) {
            const float* ipc = ip + ic * 1024 + oh * 32 + ow;
            const float* wc = ws + ic * 25;
#pragma unroll
            for (int kh = 0; kh < 5; ++kh)
#pragma unroll
                for (int kw = 0; kw < 5; ++kw)
                    acc += ipc[kh * 32 + kw] * wc[kh * 5 + kw];
        }
        c1[bc * 784 + hw] = acc;
        s += acc; sq += acc * acc;
    }
    wave_reduce2(s, sq);
    if ((tid & 63) == 0) { rs[tid >> 6] = s; rq[tid >> 6] = sq; }
    __syncthreads();
    if (tid == 0) {
        part[bc * 2]     = rs[0] + rs[1] + rs[2] + rs[3];
        part[bc * 2 + 1] = rq[0] + rq[1] + rq[2] + rq[3];
    }
}

// K2: one block per b, 1024 thr: stats1 + BN -> LDS + pool, then CONCURRENT
// {logits1 (784 thr, float4 key-broadcasts)} || {conv2 (160 thr, row-register
// caching)} -> sa + c2raw, then per-channel partials.
__global__ __launch_bounds__(1024) void stage1_kernel(
        const float* __restrict__ c1raw, const float* __restrict__ part1,
        const float* __restrict__ g1, const float* __restrict__ bb1,
        const float* __restrict__ k1s,
        const float* __restrict__ c2w, const float* __restrict__ c2b,
        float* __restrict__ out, float* __restrict__ c2raw,
        float* __restrict__ part2) {
    int b = blockIdx.x, tid = threadIdx.x;
    int lane = tid & 63, wid = tid >> 6;     // 16 waves
    __shared__ __align__(16) float act[4704];
    __shared__ __align__(16) float sk1p[512];      // [64][8]: k0..k5, K2, pad
    __shared__ float w2s[2400];
    __shared__ float xp[1176];
    __shared__ __align__(16) float sa[1600];
    __shared__ float chs[6], chq[6], ssc[6], ssh[6];
    if (wid < 6) {                            // stats1: wave = channel
        float s = 0.f, q = 0.f;
#pragma unroll
        for (int j = 0; j < 4; ++j) {
            int bi = lane + 64 * j;
            s += part1[(bi * 6 + wid) * 2];
            q += part1[(bi * 6 + wid) * 2 + 1];
        }
        wave_reduce2(s, q);
        if (lane == 0) { chs[wid] = s; chq[wid] = q; }
    }
    if (tid >= 640 && tid < 1024) {           // load keys into padded layout
        int idx = tid - 640;                  // 0..383
        int k = idx / 6, c = idx - k * 6;
        sk1p[k * 8 + c] = k1s[idx];
    }
    for (int i = tid; i < 2400; i += 1024) w2s[i] = c2w[i];
    __syncthreads();
    if (tid < 6) {
        float m = chs[tid] * (1.f / 200704.f);
        float v = chq[tid] * (1.f / 200704.f) - m * m;
        float sc = g1[tid] * rsqrtf(v + EPSV);
        ssc[tid] = sc; ssh[tid] = bb1[tid] - m * sc;
    }
    if (tid >= 64 && tid < 128) {             // key norms into slot 6 (+zero pad)
        int k = tid - 64;
        float s = 0.f;
#pragma unroll
        for (int c = 0; c < 6; ++c) { float x = sk1p[k * 8 + c]; s += x * x; }
        sk1p[k * 8 + 6] = s;
        sk1p[k * 8 + 7] = 0.f;
    }
    __syncthreads();
    for (int i = tid; i < 4704; i += 1024) {  // BN from global c1raw
        int c = i / 784;
        act[i] = c1raw[b * 4704 + i] * ssc[c] + ssh[c];
    }
    __syncthreads();
    for (int i = tid; i < 1176; i += 1024) {  // pool (all threads)
        int c = i / 196, p = i % 196, ph = p / 14, pw = p % 14;
        const float* ap = act + c * 784 + ph * 56 + pw * 2;
        float m = fmaxf(fmaxf(ap[0], ap[1]), fmaxf(ap[28], ap[29]));
        xp[i] = fmaxf(m, 0.f);
    }
    __syncthreads();
    if (tid < 784) {                          // ---- logits1: float4 key reads ----
        float a0 = act[tid], a1 = act[784 + tid], a2 = act[1568 + tid];
        float a3 = act[2352 + tid], a4 = act[3136 + tid], a5 = act[3920 + tid];
        float A2 = a0*a0 + a1*a1 + a2*a2 + a3*a3 + a4*a4 + a5*a5;
        float* op = out + OFF_L1 + (long)b * 50176 + tid;
#pragma unroll 4
        for (int k = 0; k < 64; ++k) {
            const float4* kp4 = reinterpret_cast<const float4*>(sk1p + k * 8);
            float4 kA = kp4[0], kB = kp4[1];
            float dot = a0*kA.x + a1*kA.y + a2*kA.z + a3*kA.w + a4*kB.x + a5*kB.y;
            *op = -sqrtf(fmaxf(A2 + kB.z - 2.f * dot, 0.f));
            op += 784;
        }
    } else if (tid < 944) {                   // ---- conv2: row-register caching ----
        int j = tid - 784;                    // 0..159
        int c = j / 10, oh = j - c * 10;
        float acc[10];
        float bias2 = c2b[c];
#pragma unroll
        for (int ow = 0; ow < 10; ++ow) acc[ow] = bias2;
        for (int ic = 0; ic < 6; ++ic) {
            const float* xb = xp + ic * 196;
            const float* wpc = w2s + c * 150 + ic * 25;
#pragma unroll
            for (int kh = 0; kh < 5; ++kh) {
                const float* row = xb + (oh + kh) * 14;
                float r[14];
#pragma unroll
                for (int t = 0; t < 14; ++t) r[t] = row[t];
#pragma unroll
                for (int kw = 0; kw < 5; ++kw) {
                    float wgt = wpc[kh * 5 + kw];
#pragma unroll
                    for (int ow = 0; ow < 10; ++ow)
                        acc[ow] += r[ow + kw] * wgt;
                }
            }
        }
        float* sp = sa + c * 100 + oh * 10;
        float* gp = c2raw + b * 1600 + c * 100 + oh * 10;
#pragma unroll
        for (int ow = 0; ow < 10; ++ow) { sp[ow] = acc[ow]; gp[ow] = acc[ow]; }
    }
    __syncthreads();
    {   // partials: wave = channel (16 waves)
        float s = 0.f, q = 0.f;
        if (lane < 100) { float x = sa[wid * 100 + lane]; s = x; q = x * x; }
        if (lane < 36)  { float x = sa[wid * 100 + 64 + lane]; s += x; q += x * x; }
        wave_reduce2(s, q);
        if (lane == 0) { part2[(b * 16 + wid) * 2] = s; part2[(b * 16 + wid) * 2 + 1] = q; }
    }
}

// K3: one block per b, 1024 thr: stats2, then logits2/pool read c2raw directly
// with BN applied inline (no sa staging, one fewer barrier), then fc1 + logits3
// + act4 + rank-NG loss + argmax.
__global__ __launch_bounds__(1024) void stage2_kernel(
        const float* __restrict__ c2raw, const float* __restrict__ part2,
        const float* __restrict__ g2, const float* __restrict__ bb2,
        const float* __restrict__ k2s,
        const float* __restrict__ w1t, const float* __restrict__ f1b,
        const float* __restrict__ f2w, const float* __restrict__ f2b,
        const float* __restrict__ k3st,
        float* __restrict__ out, float* __restrict__ lossb) {
    int b = blockIdx.x, tid = threadIdx.x;
    int lane = tid & 63, wid = tid >> 6;     // 16 waves
    __shared__ __align__(16) float sk2[1024];
    __shared__ float k2sq2[64];
    __shared__ float chs[16], chq[16], ssc[16], ssh[16];
    __shared__ float xs[400];
    __shared__ float partq[1024];
    __shared__ float a3r[120], a3p[120];
    __shared__ __align__(16) float sv[512];
    __shared__ __align__(16) float pv[1024];
    __shared__ int cntp[1024];
    __shared__ float wsum[8], wmv[8];
    __shared__ int wmi[8];
    {   // stats2: wave = channel
        float s = 0.f, q = 0.f;
#pragma unroll
        for (int j = 0; j < 4; ++j) {
            int bi = lane + 64 * j;
            s += part2[(bi * 16 + wid) * 2];
            q += part2[(bi * 16 + wid) * 2 + 1];
        }
        wave_reduce2(s, q);
        if (lane == 0) { chs[wid] = s; chq[wid] = q; }
    }
    sk2[tid] = k2s[tid];
    __syncthreads();
    if (tid < 16) {
        float m = chs[tid] * (1.f / 25600.f);
        float v = chq[tid] * (1.f / 25600.f) - m * m;
        float sc = g2[tid] * rsqrtf(v + EPSV);
        ssc[tid] = sc; ssh[tid] = bb2[tid] - m * sc;
    }
    if (tid >= 64 && tid < 128) {             // key norms
        int k = tid - 64;
        float s = 0.f;
#pragma unroll
        for (int c = 0; c < 16; ++c) { float x = sk2[k * 16 + c]; s += x * x; }
        k2sq2[k] = s;
    }
    __syncthreads();
    const float* cp = c2raw + b * 1600;
    if (tid < 800) {                          // logits2: BN inline from global
        int kg = tid / 100, hw = tid - kg * 100;
        float a[16], A2 = 0.f;
#pragma unroll
        for (int c = 0; c < 16; ++c) {
            a[c] = cp[c * 100 + hw] * ssc[c] + ssh[c];
            A2 += a[c] * a[c];
        }
        float* op2 = out + OFF_L2 + (long)b * 6400 + kg * 800 + hw;
#pragma unroll
        for (int k = kg * 8; k < kg * 8 + 8; ++k) {
            const float4* kp4 = reinterpret_cast<const float4*>(sk2 + k * 16);
            float4 kA = kp4[0], kB = kp4[1], kC = kp4[2], kD = kp4[3];
            float dot = a[0]*kA.x + a[1]*kA.y + a[2]*kA.z + a[3]*kA.w
                      + a[4]*kB.x + a[5]*kB.y + a[6]*kB.z + a[7]*kB.w
                      + a[8]*kC.x + a[9]*kC.y + a[10]*kC.z + a[11]*kC.w
                      + a[12]*kD.x + a[13]*kD.y + a[14]*kD.z + a[15]*kD.w;
            *op2 = -sqrtf(fmaxf(A2 + k2sq2[k] - 2.f * dot, 0.f));
            op2 += 100;
        }
    } else {                                  // pool: BN inline from global
        for (int i = tid - 800; i < 400; i += 224) {
            int c = i / 25, p = i % 25, ph = p / 5, pw = p % 5;
            const float* ap = cp + c * 100 + ph * 20 + pw * 2;
            float sc = ssc[c], sh = ssh[c];
            float v0 = ap[0] * sc + sh, v1 = ap[1] * sc + sh;
            float v2 = ap[10] * sc + sh, v3 = ap[11] * sc + sh;
            xs[i] = fmaxf(fmaxf(fmaxf(v0, v1), fmaxf(v2, v3)), 0.f);
        }
    }
    __syncthreads();
    {   // fc1: 8-way K-split, coalesced w1t columns, float2 x-broadcasts
        int o = tid & 127, q8 = tid >> 7;
        float s = 0.f;
        if (o < 120) {
            const float* wp = w1t + (q8 * 50) * 120 + o;
            const float2* xq = reinterpret_cast<const float2*>(xs + q8 * 50);
#pragma unroll 5
            for (int c2 = 0; c2 < 25; ++c2) {
                float2 xv = xq[c2];
                s += xv.x * wp[(2 * c2) * 120] + xv.y * wp[(2 * c2 + 1) * 120];
            }
        }
        partq[q8 * 128 + o] = s;
    }
    __syncthreads();
    if (tid < 120) {
        float acc = f1b[tid];
#pragma unroll
        for (int q8 = 0; q8 < 8; ++q8) acc += partq[q8 * 128 + tid];
        a3r[tid] = acc;
        a3p[tid] = fmaxf(acc, 0.f);
    }
    __syncthreads();
    {   // logits3: 2 threads per key, coalesced k3st columns
        int k = tid & 511, h = tid >> 9;
        const float* kp = k3st + k;
        float s = 0.f;
#pragma unroll 6
        for (int c = h * 60; c < h * 60 + 60; ++c) {
            float d = a3r[c] - kp[c * 512];
            s += d * d;
        }
        pv[h * 512 + k] = s;
    }
    if (tid < 10) {
        float acc = f2b[tid];
        const float* wp = f2w + tid * 120;
#pragma unroll 8
        for (int c = 0; c < 120; ++c) acc += a3p[c] * wp[c];
        out[OFF_ACT4 + b * 10 + tid] = acc;
    }
    __syncthreads();
    if (tid < 512) {
        float v = -sqrtf(pv[tid] + pv[512 + tid]);
        sv[tid] = v;
        out[OFF_L3 + (long)b * 512 + tid] = v;
    }
    __syncthreads();
    {   // rank scan: 2 threads per value
        int i = tid & 511, h = tid >> 9;
        float v = sv[i];
        const float4* sv4 = reinterpret_cast<const float4*>(sv);
        int cnt = 0;
#pragma unroll 8
        for (int j4 = h * 64; j4 < h * 64 + 64; ++j4) {
            float4 o4 = sv4[j4];
            int jb = j4 * 4;
            cnt += (o4.x < v || (o4.x == v && jb < i)) ? 1 : 0;
            cnt += (o4.y < v || (o4.y == v && jb + 1 < i)) ? 1 : 0;
            cnt += (o4.z < v || (o4.z == v && jb + 2 < i)) ? 1 : 0;
            cnt += (o4.w < v || (o4.w == v && jb + 3 < i)) ? 1 : 0;
        }
        cntp[h * 512 + i] = cnt;
    }
    __syncthreads();
    if (tid < 512) {
        float v = sv[tid];
        int cnt = cntp[tid] + cntp[512 + tid];
        float contrib = v * v * expf(-(float)cnt);
        float ssum = contrib;
#pragma unroll
        for (int o = 32; o > 0; o >>= 1) ssum += __shfl_down(ssum, o, 64);
        float mv = v; int mi = tid;
#pragma unroll
        for (int o = 32; o > 0; o >>= 1) {
            float ov = __shfl_down(mv, o, 64);
            int oi = __shfl_down(mi, o, 64);
            if (ov > mv || (ov == mv && oi < mi)) { mv = ov; mi = oi; }
        }
        if (lane == 0) { wsum[wid] = ssum; wmv[wid] = mv; wmi[wid] = mi; }
    }
    __syncthreads();
    if (tid == 0) {
        float tot = 0.f;
        float bmv = wmv[0]; int bmi = wmi[0];
#pragma unroll
        for (int w = 0; w < 8; ++w) {
            tot += wsum[w];
            if (wmv[w] > bmv || (wmv[w] == bmv && wmi[w] < bmi)) { bmv = wmv[w]; bmi = wmi[w]; }
        }
        lossb[b] = tot;
        out[OFF_ASSIGN + b] = (float)bmi;
    }
}

__global__ void final_kernel(const float* __restrict__ loss_b, float* __restrict__ out_loss) {
    __shared__ float r[256];
    int tid = threadIdx.x;
    r[tid] = loss_b[tid];
    __syncthreads();
    for (int s = 128; s > 0; s >>= 1) {
        if (tid < s) r[tid] += r[tid + s];
        __syncthreads();
    }
    if (tid == 0) out_loss[0] = r[0] / 256.f;
}

extern "C" void kernel_launch(void* const* d_in, const int* in_sizes, int n_in,
                              void* d_out, int out_size, void* d_ws, size_t ws_size,
                              hipStream_t stream) {
    const float* inp = (const float*)d_in[0];
    const float* c1w = (const float*)d_in[1];
    const float* c1b = (const float*)d_in[2];
    const float* g1  = (const float*)d_in[3];
    const float* bb1 = (const float*)d_in[4];
    const float* c2w = (const float*)d_in[5];
    const float* c2b = (const float*)d_in[6];
    const float* g2  = (const float*)d_in[7];
    const float* bb2 = (const float*)d_in[8];
    const float* f1w = (const float*)d_in[9];
    const float* f1b = (const float*)d_in[10];
    const float* f2w = (const float*)d_in[11];
    const float* f2b = (const float*)d_in[12];
    const float* k1  = (const float*)d_in[13];
    const float* k2  = (const float*)d_in[14];
    const float* k3  = (const float*)d_in[15];
    float* out = (float*)d_out;

    float* W = (float*)d_ws;
    float* part1 = W + 64;              // 3072
    float* c1raw = W + 3136;            // 1204224
    float* c2raw = W + 1207360;         // 409600
    float* part2 = W + 1616960;         // 8192
    float* lossb = W + 1625152;         // 256
    float* w1t   = W + 1625408;         // 48000
    float* k3st  = W + 1673408;         // 61440

    conv1_kernel<<<1964, 256, 0, stream>>>(inp, c1w, c1b, c1raw, part1,
                                           f1w, k3, w1t, k3st);
    stage1_kernel<<<B, 1024, 0, stream>>>(c1raw, part1, g1, bb1, k1, c2w, c2b,
                                          out, c2raw, part2);
    stage2_kernel<<<B, 1024, 0, stream>>>(c2raw, part2, g2, bb2, k2,
                                          w1t, f1b, f2w, f2b, k3st, out, lossb);
    final_kernel<<<1, 256, 0, stream>>>(lossb, out + OFF_LOSS);
}